// Round 2
// 2669.635 us; speedup vs baseline: 1.2480x; 1.2480x over previous
//
#include <hip/hip_runtime.h>

#define SEQ 512
#define EDIM 512
#define NHEAD 8
#define HDIM 64
#define NBATCH 8
#define ROWS (NBATCH * SEQ) /* 4096 */
#define QKV_N (3 * EDIM)    /* 1536 */
#define TGTV 8000
#define HID2 16000
#define LN_EPS 1e-3f

#define BM 128
#define BN 128
#define BK 32

typedef unsigned short u16;
typedef __bf16 bf16x8 __attribute__((ext_vector_type(8)));
typedef float f32x4 __attribute__((ext_vector_type(4)));

__device__ __forceinline__ float b2f(u16 x) {
  unsigned int u = ((unsigned int)x) << 16;
  float f;
  __builtin_memcpy(&f, &u, 4);
  return f;
}
__device__ __forceinline__ u16 f2b(float f) {
  unsigned int u;
  __builtin_memcpy(&u, &f, 4);
  u = (u + 0x7fffu + ((u >> 16) & 1u)) >> 16;  // RNE
  return (u16)u;
}

__device__ __forceinline__ void async_copy16(const void* g, void* l) {
  __builtin_amdgcn_global_load_lds(
      (const __attribute__((address_space(1))) unsigned int*)g,
      (__attribute__((address_space(3))) unsigned int*)l, 16, 0, 0);
}

// ---------------------------------------------------------------------------
// C[M,N] = A[M,K](bf16,row-major,lda) @ Bt[N,K](bf16,row-major,ldb)^T
// + optional bias[N]; flags: bit0 = relu, bit1 = bf16 output (else f32).
// Batched: blockIdx.z -> (zb, zh) with zh = z % nbh. All strides in elements.
// ---------------------------------------------------------------------------
__global__ __launch_bounds__(256) void gemm_bt(
    const u16* __restrict__ A, const u16* __restrict__ B, void* __restrict__ C,
    const float* __restrict__ bias, int M, int N, int K, int lda, int ldb,
    int ldc, long abb, long abh, long bbb, long bbh, long cbb, long cbh,
    int nbh, int flags) {
  __shared__ __align__(16) u16 lsA[BM * BK];  // [m][k]
  __shared__ __align__(16) u16 lsB[BN * BK];  // [n][k]
  const int tid = threadIdx.x;
  const int wave = tid >> 6, lane = tid & 63;
  const int quad = lane >> 4, l16 = lane & 15;
  const int wm = (wave & 1) << 6, wn = (wave >> 1) << 6;

  const int z = blockIdx.z;
  const int zb = z / nbh, zh = z - zb * nbh;
  const u16* Ab = A + zb * abb + zh * abh;
  const u16* Bb = B + zb * bbb + zh * bbh;
  const long coff = zb * cbb + zh * cbh;
  const int m0 = blockIdx.y * BM, n0 = blockIdx.x * BN;

  f32x4 acc[4][4];
#pragma unroll
  for (int i = 0; i < 4; ++i)
#pragma unroll
    for (int j = 0; j < 4; ++j) acc[i][j] = (f32x4)0.0f;

  const int srow = tid >> 2;           // 0..63
  const int skc = (tid & 3) << 3;      // k offset 0/8/16/24
  const u16* ga0 = Ab + (long)(m0 + srow) * lda + skc;
  const u16* ga1 = ga0 + 64L * lda;
  const u16* gb0 = Bb + (long)(n0 + srow) * ldb + skc;
  const u16* gb1 = gb0 + 64L * ldb;
  u16* la0 = &lsA[(wave << 6) * 8];
  u16* la1 = &lsA[(256 + (wave << 6)) * 8];
  u16* lb0 = &lsB[(wave << 6) * 8];
  u16* lb1 = &lsB[(256 + (wave << 6)) * 8];

  for (int k0 = 0; k0 < K; k0 += BK) {
    async_copy16(ga0 + k0, la0);
    async_copy16(ga1 + k0, la1);
    async_copy16(gb0 + k0, lb0);
    async_copy16(gb1 + k0, lb1);
    __syncthreads();
    bf16x8 af[4], bfr[4];
#pragma unroll
    for (int i = 0; i < 4; ++i)
      af[i] = *(const bf16x8*)&lsA[(wm + (i << 4) + l16) * BK + (quad << 3)];
#pragma unroll
    for (int j = 0; j < 4; ++j)
      bfr[j] = *(const bf16x8*)&lsB[(wn + (j << 4) + l16) * BK + (quad << 3)];
#pragma unroll
    for (int i = 0; i < 4; ++i)
#pragma unroll
      for (int j = 0; j < 4; ++j)
        acc[i][j] = __builtin_amdgcn_mfma_f32_16x16x32_bf16(af[i], bfr[j],
                                                            acc[i][j], 0, 0, 0);
    __syncthreads();
  }

  const int relu = flags & 1, obf = flags & 2;
  float bv[4];
#pragma unroll
  for (int j = 0; j < 4; ++j) {
    int col = n0 + wn + (j << 4) + l16;
    bv[j] = (bias != nullptr && col < N) ? bias[col] : 0.0f;
  }
#pragma unroll
  for (int i = 0; i < 4; ++i) {
    int rbase = m0 + wm + (i << 4) + (quad << 2);
#pragma unroll
    for (int j = 0; j < 4; ++j) {
      int col = n0 + wn + (j << 4) + l16;
      if (col < N) {
#pragma unroll
        for (int r = 0; r < 4; ++r) {
          float v = acc[i][j][r] + bv[j];
          if (relu) v = fmaxf(v, 0.0f);
          long idx = coff + (long)(rbase + r) * ldc + col;
          if (obf)
            ((u16*)C)[idx] = f2b(v);
          else
            ((float*)C)[idx] = v;
        }
      }
    }
  }
}

// ---------------------------------------------------------------------------
// 256x256 8-wave phase-split pipelined GEMM for the big classifier matmuls.
// C[M,N] = A[M,K] @ Bt[N,K]^T + bias; flags bit0=relu, bit1=bf16 out.
// Requirements: M % 256 == 0, K % 64 == 0, K >= 192. B rows are CLAMPED to
// nblast (last allocated row) so no allocation padding beyond nblast+1 rows
// is needed; clamped rows feed only store-masked columns (col >= N).
// Techniques: T1 bijective XCD swizzle (M-fastest decomp), T2 st_16x32 LDS
// swizzle via pre-swizzled global source (global_load_lds writes linearly),
// T3/T4 phase-split K-loop with counted vmcnt (never 0 mid-loop) + raw
// s_barrier, T5 setprio around the MFMA cluster.
// Race safety: stage of K-tile t+2 (same LDS buffer as t) is issued only
// AFTER the barrier that ends t's last read phase; its landing is waited
// (counted vmcnt) + barrier'd one full K-tile later.
// ---------------------------------------------------------------------------
__global__ __launch_bounds__(512, 2) void gemm_big(
    const u16* __restrict__ A, const u16* __restrict__ B, void* __restrict__ C,
    const float* __restrict__ bias, int M, int N, int K, int lda, int ldb,
    int ldc, int nblast, int flags) {
  // [dbuf][A=0/B=1][half][128 rows x 64 cols] ; 131072 B total
  __shared__ __align__(16) u16 lds[2][2][2][8192];
  const int tid = threadIdx.x;
  const int wave = tid >> 6, lane = tid & 63;
  const int quad = lane >> 4, l16 = lane & 15;
  const int wmi = wave >> 2, wni = wave & 3;  // 2 x 4 wave grid
  (void)M;

  // T1: bijective XCD swizzle on linear wg id, then M-fastest decomposition
  // (consecutive wg share the B-panel; each XCD owns disjoint B-panels).
  const int gx = gridDim.x, gy = gridDim.y;
  const int nwg = gx * gy;
  const int orig = blockIdx.y * gx + blockIdx.x;
  const int q8 = nwg >> 3, r8 = nwg & 7;
  const int xcd = orig & 7, i8 = orig >> 3;
  const int wg =
      (xcd < r8 ? xcd * (q8 + 1) : r8 * (q8 + 1) + (xcd - r8) * q8) + i8;
  const int m0 = (wg % gy) * 256;
  const int n0 = (wg / gy) * 256;

  // ---- staging: pre-swizzled global source ----
  // linear dest byte o = c*8192 + tid*16 ; st_16x32: o ^= ((o>>9)&1)<<5
  // o bit9 == tid bit5 ; flipping o bit5 == flipping tid bit1.
  const int stid = tid ^ (((tid >> 5) & 1) << 1);
  const int srow = stid >> 3;        // 0..63 within a 64-row chunk
  const int scol = (stid & 7) << 3;  // element col 0,8,..,56
  const u16* gA00 = A + (long)(m0 + srow) * lda + scol;
  const u16* gA01 = A + (long)(m0 + 64 + srow) * lda + scol;
  const u16* gA10 = A + (long)(m0 + 128 + srow) * lda + scol;
  const u16* gA11 = A + (long)(m0 + 192 + srow) * lda + scol;
  const int rb0 = min(n0 + srow, nblast);
  const int rb1 = min(n0 + 64 + srow, nblast);
  const int rb2 = min(n0 + 128 + srow, nblast);
  const int rb3 = min(n0 + 192 + srow, nblast);
  const u16* gB00 = B + (long)rb0 * ldb + scol;
  const u16* gB01 = B + (long)rb1 * ldb + scol;
  const u16* gB10 = B + (long)rb2 * ldb + scol;
  const u16* gB11 = B + (long)rb3 * ldb + scol;
  u16* lp = &lds[0][0][0][0];
  const int wo = wave << 9;  // wave's 1 KiB slot (512 u16)

// element offsets: dbuf stride 32768, A/B stride 16384, half stride 8192,
// chunk(c) stride 4096
#define STAGE(DD, KOFF)                              \
  do {                                               \
    u16* lb_ = lp + (DD) * 32768 + wo;               \
    async_copy16(gA00 + (KOFF), lb_ + 0);            \
    async_copy16(gA01 + (KOFF), lb_ + 4096);         \
    async_copy16(gA10 + (KOFF), lb_ + 8192);         \
    async_copy16(gA11 + (KOFF), lb_ + 12288);        \
    async_copy16(gB00 + (KOFF), lb_ + 16384);        \
    async_copy16(gB01 + (KOFF), lb_ + 20480);        \
    async_copy16(gB10 + (KOFF), lb_ + 24576);        \
    async_copy16(gB11 + (KOFF), lb_ + 28672);        \
  } while (0)

  // ---- fragment read addressing (swizzled) ----
  // A frag (mf,ks): byte = wmi*16384 + (mf*16+l16)*128 + ((ks*64+quad*16)^rxor)
  // rxor = ((row>>2)&1)<<5 ; row bit2 == l16 bit2 (mf*16 has bit2==0).
  const int rxor = ((l16 >> 2) & 1) << 5;
  const int kq0 = (quad << 4) ^ rxor;
  const int kq1 = (64 | (quad << 4)) ^ rxor;
  const char* ldsc = (const char*)lp;

  f32x4 acc[8][4];
#pragma unroll
  for (int i = 0; i < 8; ++i)
#pragma unroll
    for (int j = 0; j < 4; ++j) acc[i][j] = (f32x4)0.0f;
  bf16x8 af[4][2];   // current qm's A frags
  bf16x8 bfr[2][2];  // current qn's B frags

#define LDA_Q(QM)                                                             \
  do {                                                                        \
    const char* pa_ =                                                         \
        ldsc + dOff + (wmi << 14) + ((QM) << 13) + (l16 << 7);                \
    _Pragma("unroll") for (int mf4 = 0; mf4 < 4; ++mf4) {                     \
      af[mf4][0] = *(const bf16x8*)(pa_ + mf4 * 2048 + kq0);                  \
      af[mf4][1] = *(const bf16x8*)(pa_ + mf4 * 2048 + kq1);                  \
    }                                                                         \
  } while (0)

#define LDB_Q(QN)                                                             \
  do {                                                                        \
    const char* pb_ = ldsc + dOff + 32768 + ((wni >> 1) << 14) +              \
                      ((wni & 1) << 13) + ((QN) << 12) + (l16 << 7);          \
    _Pragma("unroll") for (int nf2 = 0; nf2 < 2; ++nf2) {                     \
      bfr[nf2][0] = *(const bf16x8*)(pb_ + nf2 * 2048 + kq0);                 \
      bfr[nf2][1] = *(const bf16x8*)(pb_ + nf2 * 2048 + kq1);                 \
    }                                                                         \
  } while (0)

#define MMA_Q(QM, QN)                                                         \
  do {                                                                        \
    __builtin_amdgcn_s_setprio(1);                                            \
    _Pragma("unroll") for (int ks = 0; ks < 2; ++ks)                          \
        _Pragma("unroll") for (int mf4 = 0; mf4 < 4; ++mf4)                   \
            _Pragma("unroll") for (int nf2 = 0; nf2 < 2; ++nf2)               \
                acc[(QM) * 4 + mf4][(QN) * 2 + nf2] =                         \
        __builtin_amdgcn_mfma_f32_16x16x32_bf16(                              \
            af[mf4][ks], bfr[nf2][ks], acc[(QM) * 4 + mf4][(QN) * 2 + nf2],   \
            0, 0, 0);                                                         \
    __builtin_amdgcn_s_setprio(0);                                            \
  } while (0)

#define BAR()                          \
  do {                                 \
    asm volatile("" ::: "memory");     \
    __builtin_amdgcn_s_barrier();      \
    asm volatile("" ::: "memory");     \
  } while (0)

  const int NT = K >> 6;  // K-tiles of 64 (NT >= 3 for all callers)
  STAGE(0, 0L);
  STAGE(1, 64L);

  for (int t = 0; t < NT; ++t) {
    const int dOff = (t & 1) * 65536;  // dbuf byte offset
    // wait this tile's 8 loads (counted: tile t+1's 8 may stay in flight)
    if (t + 1 < NT)
      asm volatile("s_waitcnt vmcnt(8)" ::: "memory");
    else
      asm volatile("s_waitcnt vmcnt(0)" ::: "memory");
    BAR();  // all waves' staging of tile t visible
    // snake over C quadrants: (0,0) -> (0,1) -> (1,1) -> (1,0)
    LDA_Q(0);
    LDB_Q(0);
    MMA_Q(0, 0);
    BAR();
    LDB_Q(1);
    MMA_Q(0, 1);
    BAR();
    LDA_Q(1);
    MMA_Q(1, 1);
    BAR();
    LDB_Q(0);
    MMA_Q(1, 0);
    BAR();  // all reads of buffer (t&1) complete across the block
    if (t + 2 < NT) STAGE(t & 1, (long)(t + 2) << 6);
  }

#undef STAGE
#undef LDA_Q
#undef LDB_Q
#undef MMA_Q
#undef BAR

  const int relu = flags & 1, obf = flags & 2;
  float bv[4];
#pragma unroll
  for (int nf = 0; nf < 4; ++nf) {
    int col = n0 + (wni << 6) + (nf << 4) + l16;
    bv[nf] = (bias != nullptr && col < N) ? bias[col] : 0.0f;
  }
#pragma unroll
  for (int mf = 0; mf < 8; ++mf) {
    int rbase = m0 + (wmi << 7) + (mf << 4) + (quad << 2);
#pragma unroll
    for (int nf = 0; nf < 4; ++nf) {
      int col = n0 + (wni << 6) + (nf << 4) + l16;
      if (col < N) {
#pragma unroll
        for (int r = 0; r < 4; ++r) {
          float v = acc[mf][nf][r] + bv[nf];
          if (relu) v = fmaxf(v, 0.0f);
          long idx = (long)(rbase + r) * ldc + col;
          if (obf)
            ((u16*)C)[idx] = f2b(v);
          else
            ((float*)C)[idx] = v;
        }
      }
    }
  }
}

// ---------------------------------------------------------------------------
// out[n*out_ld + k] = bf16(in[k*in_ld + n]); 2-level batch (b0,b1).
// ---------------------------------------------------------------------------
__device__ __forceinline__ float cvt_f(float x) { return x; }
__device__ __forceinline__ float cvt_f(u16 x) { return b2f(x); }

template <typename T>
__global__ __launch_bounds__(256) void transpose_k(
    const T* __restrict__ in, u16* __restrict__ out, int K, int N, int in_ld,
    int out_ld, long ib0, long ib1, long ob0, long ob1, int nb1) {
  __shared__ float tile[32][33];
  const int z = blockIdx.z;
  const int b0 = z / nb1, b1 = z - b0 * nb1;
  const T* ip = in + b0 * ib0 + b1 * ib1;
  u16* op = out + b0 * ob0 + b1 * ob1;
  const int tx = threadIdx.x & 31, ty = threadIdx.x >> 5;  // 32 x 8
  const int n = blockIdx.x * 32 + tx;
  const int kb = blockIdx.y * 32;
#pragma unroll
  for (int i = ty; i < 32; i += 8) {
    int k = kb + i;
    if (k < K && n < N) tile[i][tx] = cvt_f(ip[(long)k * in_ld + n]);
  }
  __syncthreads();
  const int k2 = kb + tx;
#pragma unroll
  for (int i = ty; i < 32; i += 8) {
    int n2 = blockIdx.x * 32 + i;
    if (k2 < K && n2 < N) op[(long)n2 * out_ld + k2] = f2b(tile[tx][i]);
  }
}

// ---------------------------------------------------------------------------
__device__ __forceinline__ float wave_red_max(float v) {
#pragma unroll
  for (int o = 32; o > 0; o >>= 1) v = fmaxf(v, __shfl_xor(v, o, 64));
  return v;
}
__device__ __forceinline__ float wave_red_sum(float v) {
#pragma unroll
  for (int o = 32; o > 0; o >>= 1) v += __shfl_xor(v, o, 64);
  return v;
}

// one block (256 thr) per row of 512 logits; scale & causal mask folded in.
__global__ __launch_bounds__(256) void softmax_k(const float* __restrict__ Sc,
                                                 u16* __restrict__ P,
                                                 int causal) {
  __shared__ float red[4];
  const int row = blockIdx.x;
  const int q = row & (SEQ - 1);
  const float* s = Sc + (long)row * SEQ;
  u16* p = P + (long)row * SEQ;
  const int lim = causal ? q : (SEQ - 1);
  const int t = threadIdx.x;
  const int wave = t >> 6, lane = t & 63;
  const float scale = 0.044194173824159216f;  // 1/sqrt(512)
  float v0 = (t <= lim) ? s[t] * scale : -3.0e38f;
  float v1 = (t + 256 <= lim) ? s[t + 256] * scale : -3.0e38f;
  float mxw = wave_red_max(fmaxf(v0, v1));
  if (lane == 0) red[wave] = mxw;
  __syncthreads();
  float mx = fmaxf(fmaxf(red[0], red[1]), fmaxf(red[2], red[3]));
  __syncthreads();
  float e0 = (t <= lim) ? expf(v0 - mx) : 0.0f;
  float e1 = (t + 256 <= lim) ? expf(v1 - mx) : 0.0f;
  float smw = wave_red_sum(e0 + e1);
  if (lane == 0) red[wave] = smw;
  __syncthreads();
  float inv = 1.0f / (red[0] + red[1] + red[2] + red[3]);
  p[t] = f2b(e0 * inv);
  p[t + 256] = f2b(e1 * inv);
}

// O = [relu](LN(Xa + Xb)) ; one block per row of 512
__global__ __launch_bounds__(256) void add_ln_k(
    const u16* __restrict__ Xa, const u16* __restrict__ Xb,
    const float* __restrict__ g, const float* __restrict__ be,
    u16* __restrict__ O, int relu) {
  __shared__ float red[8];
  const int row = blockIdx.x;
  const int t = threadIdx.x;
  const int wave = t >> 6, lane = t & 63;
  const long base = (long)row * EDIM;
  float x0 = b2f(Xa[base + t]) + b2f(Xb[base + t]);
  float x1 = b2f(Xa[base + t + 256]) + b2f(Xb[base + t + 256]);
  float s = wave_red_sum(x0 + x1);
  float s2 = wave_red_sum(x0 * x0 + x1 * x1);
  if (lane == 0) {
    red[wave] = s;
    red[wave + 4] = s2;
  }
  __syncthreads();
  s = red[0] + red[1] + red[2] + red[3];
  s2 = red[4] + red[5] + red[6] + red[7];
  float mean = s * (1.0f / EDIM);
  float var = s2 * (1.0f / EDIM) - mean * mean;
  float r = rsqrtf(var + LN_EPS);
  float y0 = (x0 - mean) * r * g[t] + be[t];
  float y1 = (x1 - mean) * r * g[t + 256] + be[t + 256];
  if (relu) {
    y0 = fmaxf(y0, 0.0f);
    y1 = fmaxf(y1, 0.0f);
  }
  O[base + t] = f2b(y0);
  O[base + t + 256] = f2b(y1);
}

// out[row] = emb[ids[row]] * sqrt(E) + pos(row % SEQ)
__global__ __launch_bounds__(256) void embed_k(const int* __restrict__ ids,
                                               const float* __restrict__ emb,
                                               u16* __restrict__ out) {
  const int row = blockIdx.x;
  const int t = threadIdx.x;
  const int s = row & (SEQ - 1);
  const int id = ids[row];
  const float* e = emb + (long)id * EDIM;
  const long base = (long)row * EDIM;
#pragma unroll
  for (int i = 0; i < 2; ++i) {
    int c = t + i * 256;
    int j = (c < 256) ? c : c - 256;
    float ang = (float)s * expf(-9.210340371976184f * ((float)j * (1.0f / 256.0f)));
    float pos = (c < 256) ? sinf(ang) : cosf(ang);
    out[base + c] = f2b(e[c] * 22.627416997969522f + pos);
  }
}

// ---------------------------------------------------------------------------
extern "C" void kernel_launch(void* const* d_in, const int* in_sizes, int n_in,
                              void* d_out, int out_size, void* d_ws,
                              size_t ws_size, hipStream_t stream) {
  const int* src_ids = (const int*)d_in[0];
  const int* tgt_ids = (const int*)d_in[1];
  const float* src_emb = (const float*)d_in[2];
  const float* tgt_emb = (const float*)d_in[3];
  const float* enc_wk = (const float*)d_in[4];
  const float* enc_wv = (const float*)d_in[5];
  const float* enc_wq = (const float*)d_in[6];
  const float* enc_dw = (const float*)d_in[7];
  const float* enc_db = (const float*)d_in[8];
  const float* enc_ffw = (const float*)d_in[9];
  const float* enc_ffb = (const float*)d_in[10];
  const float* enc_ln_g = (const float*)d_in[11];
  const float* enc_ln_b = (const float*)d_in[12];
  const float* dec_swk = (const float*)d_in[13];
  const float* dec_swv = (const float*)d_in[14];
  const float* dec_swq = (const float*)d_in[15];
  const float* dec_sdw = (const float*)d_in[16];
  const float* dec_sdb = (const float*)d_in[17];
  const float* dec_cwk = (const float*)d_in[18];
  const float* dec_cwv = (const float*)d_in[19];
  const float* dec_cwq = (const float*)d_in[20];
  const float* dec_cdw = (const float*)d_in[21];
  const float* dec_cdb = (const float*)d_in[22];
  const float* dec_ffw = (const float*)d_in[23];
  const float* dec_ffb = (const float*)d_in[24];
  const float* dec_ln_g = (const float*)d_in[25];
  const float* dec_ln_b = (const float*)d_in[26];
  const float* cls_w1 = (const float*)d_in[27];
  const float* cls_b1 = (const float*)d_in[28];
  const float* cls_w2 = (const float*)d_in[29];
  const float* cls_b2 = (const float*)d_in[30];
  (void)in_sizes; (void)n_in; (void)out_size; (void)ws_size;

  char* wsp = (char*)d_ws;
  size_t off = 0;
  auto alloc = [&](size_t bytes) -> char* {
    char* p = wsp + off;
    off += (bytes + 255) & ~(size_t)255;
    return p;
  };
  // workspace layout byte-identical to the previously-verified session
  u16* x_bf = (u16*)alloc((size_t)ROWS * EDIM * 2);
  u16* y_bf = (u16*)alloc((size_t)ROWS * EDIM * 2);
  u16* wqkv_e = (u16*)alloc((size_t)QKV_N * EDIM * 2);
  u16* wqkv_s = (u16*)alloc((size_t)QKV_N * EDIM * 2);
  u16* wqkv_c = (u16*)alloc((size_t)QKV_N * EDIM * 2);
  u16* t_encdw = (u16*)alloc((size_t)EDIM * EDIM * 2);
  u16* t_encff = (u16*)alloc((size_t)EDIM * EDIM * 2);
  u16* t_sdw = (u16*)alloc((size_t)EDIM * EDIM * 2);
  u16* t_cdw = (u16*)alloc((size_t)EDIM * EDIM * 2);
  u16* t_decff = (u16*)alloc((size_t)EDIM * EDIM * 2);
  u16* w1t = (u16*)alloc((size_t)HID2 * EDIM * 2);
  u16* w2t = (u16*)alloc((size_t)8064 * HID2 * 2);  // N padded 8000->8064
  u16* qkv = (u16*)alloc((size_t)ROWS * QKV_N * 2);
  float* scores = (float*)alloc((size_t)64 * SEQ * SEQ * 4);
  u16* pbf = (u16*)alloc((size_t)64 * SEQ * SEQ * 2);
  u16* vt = (u16*)alloc((size_t)64 * 128 * SEQ * 2);  // d padded 64->128
  u16* att = (u16*)alloc((size_t)ROWS * EDIM * 2);
  u16* tmp = (u16*)alloc((size_t)ROWS * EDIM * 2);
  u16* hbf = (u16*)alloc((size_t)ROWS * EDIM * 2);
  u16* enc_o = (u16*)alloc((size_t)ROWS * EDIM * 2);
  u16* h1 = (u16*)alloc((size_t)ROWS * EDIM * 2);
  u16* h2 = (u16*)alloc((size_t)ROWS * EDIM * 2);
  u16* dec_o = (u16*)alloc((size_t)ROWS * EDIM * 2);
  u16* hid = (u16*)alloc((size_t)ROWS * HID2 * 2);

  auto gemm = [&](const u16* A, const u16* Bt, void* C, const float* bias,
                  int M, int N, int K, int lda, int ldb, int ldc, long abb,
                  long abh, long bbb, long bbh, long cbb, long cbh, int nbh,
                  int nz, int flags) {
    dim3 grid((N + BN - 1) / BN, (M + BM - 1) / BM, nz);
    gemm_bt<<<grid, dim3(256), 0, stream>>>(A, Bt, C, bias, M, N, K, lda, ldb,
                                            ldc, abb, abh, bbb, bbh, cbb, cbh,
                                            nbh, flags);
  };
  auto gemm_big_l = [&](const u16* A, const u16* Bt, void* C,
                        const float* bias, int M, int N, int K, int lda,
                        int ldb, int ldc, int nblast, int flags) {
    dim3 grid((N + 255) / 256, M / 256, 1);
    gemm_big<<<grid, dim3(512), 0, stream>>>(A, Bt, C, bias, M, N, K, lda,
                                             ldb, ldc, nblast, flags);
  };
  auto trf = [&](const float* in, u16* out, int K, int N, int ild, int old_,
                 long ib0, long ib1, long ob0, long ob1, int nb0, int nb1) {
    dim3 grid((N + 31) / 32, (K + 31) / 32, nb0 * nb1);
    transpose_k<float><<<grid, dim3(256), 0, stream>>>(in, out, K, N, ild,
                                                       old_, ib0, ib1, ob0,
                                                       ob1, nb1);
  };
  auto trb = [&](const u16* in, u16* out, int K, int N, int ild, int old_,
                 long ib0, long ib1, long ob0, long ob1, int nb0, int nb1) {
    dim3 grid((N + 31) / 32, (K + 31) / 32, nb0 * nb1);
    transpose_k<u16><<<grid, dim3(256), 0, stream>>>(in, out, K, N, ild, old_,
                                                     ib0, ib1, ob0, ob1, nb1);
  };

  // embeddings
  embed_k<<<dim3(ROWS), dim3(256), 0, stream>>>(src_ids, src_emb, x_bf);
  embed_k<<<dim3(ROWS), dim3(256), 0, stream>>>(tgt_ids, tgt_emb, y_bf);

  // weight repacks: w[h][e][d] -> wt[(h*64+d)][e], packed [Q|K|V] rows
  auto repack_qkv = [&](const float* wq, const float* wk, const float* wv,
                        u16* dst) {
    trf(wq, dst, EDIM, HDIM, HDIM, EDIM, 0, (long)EDIM * HDIM, 0,
        (long)HDIM * EDIM, 1, NHEAD);
    trf(wk, dst + EDIM * EDIM, EDIM, HDIM, HDIM, EDIM, 0, (long)EDIM * HDIM, 0,
        (long)HDIM * EDIM, 1, NHEAD);
    trf(wv, dst + 2 * EDIM * EDIM, EDIM, HDIM, HDIM, EDIM, 0,
        (long)EDIM * HDIM, 0, (long)HDIM * EDIM, 1, NHEAD);
  };
  repack_qkv(enc_wq, enc_wk, enc_wv, wqkv_e);
  repack_qkv(dec_swq, dec_swk, dec_swv, wqkv_s);
  repack_qkv(dec_cwq, dec_cwk, dec_cwv, wqkv_c);
  trf(enc_dw, t_encdw, EDIM, EDIM, EDIM, EDIM, 0, 0, 0, 0, 1, 1);
  trf(enc_ffw, t_encff, EDIM, EDIM, EDIM, EDIM, 0, 0, 0, 0, 1, 1);
  trf(dec_sdw, t_sdw, EDIM, EDIM, EDIM, EDIM, 0, 0, 0, 0, 1, 1);
  trf(dec_cdw, t_cdw, EDIM, EDIM, EDIM, EDIM, 0, 0, 0, 0, 1, 1);
  trf(dec_ffw, t_decff, EDIM, EDIM, EDIM, EDIM, 0, 0, 0, 0, 1, 1);
  trf(cls_w1, w1t, EDIM, HID2, HID2, EDIM, 0, 0, 0, 0, 1, 1);
  trf(cls_w2, w2t, HID2, TGTV, TGTV, HID2, 0, 0, 0, 0, 1, 1);

  const long SB = (long)SEQ * QKV_N;  // 786432
  const long SS = (long)SEQ * SEQ;    // 262144
  const long VTB = 128L * SEQ;        // 65536

  // shared attention stage: qkv holds [Q|K|V] per token row
  auto attention = [&](int causal) {
    trb(qkv + 2 * EDIM, vt, SEQ, HDIM, QKV_N, SEQ, SB, HDIM, 8 * VTB, VTB,
        NBATCH, NHEAD);
    gemm(qkv, qkv + EDIM, scores, nullptr, SEQ, SEQ, HDIM, QKV_N, QKV_N, SEQ,
         SB, HDIM, SB, HDIM, 8 * SS, SS, NHEAD, 64, 0);
    softmax_k<<<dim3(64 * SEQ), dim3(256), 0, stream>>>(scores, pbf, causal);
    gemm(pbf, vt, att, nullptr, SEQ, HDIM, SEQ, SEQ, SEQ, EDIM, 8 * SS, SS,
         8 * VTB, VTB, (long)SEQ * EDIM, HDIM, NHEAD, 64, 2);
  };

  // ---- encoder ----
  gemm(x_bf, wqkv_e, qkv, nullptr, ROWS, QKV_N, EDIM, EDIM, EDIM, QKV_N, 0, 0,
       0, 0, 0, 0, 1, 1, 2);
  attention(1);
  gemm(att, t_encdw, tmp, enc_db, ROWS, EDIM, EDIM, EDIM, EDIM, EDIM, 0, 0, 0,
       0, 0, 0, 1, 1, 2);
  add_ln_k<<<dim3(ROWS), dim3(256), 0, stream>>>(x_bf, tmp, enc_ln_g, enc_ln_b,
                                                 hbf, 0);
  gemm(hbf, t_encff, tmp, enc_ffb, ROWS, EDIM, EDIM, EDIM, EDIM, EDIM, 0, 0, 0,
       0, 0, 0, 1, 1, 2);
  add_ln_k<<<dim3(ROWS), dim3(256), 0, stream>>>(hbf, tmp, enc_ln_g, enc_ln_b,
                                                 enc_o, 0);

  // ---- decoder self-attention ----
  gemm(y_bf, wqkv_s, qkv, nullptr, ROWS, QKV_N, EDIM, EDIM, EDIM, QKV_N, 0, 0,
       0, 0, 0, 0, 1, 1, 2);
  attention(1);
  gemm(att, t_sdw, tmp, dec_sdb, ROWS, EDIM, EDIM, EDIM, EDIM, EDIM, 0, 0, 0,
       0, 0, 0, 1, 1, 2);
  add_ln_k<<<dim3(ROWS), dim3(256), 0, stream>>>(y_bf, tmp, dec_ln_g, dec_ln_b,
                                                 h1, 0);

  // ---- decoder cross-attention: Q from h1, K/V from enc_out ----
  gemm(h1, wqkv_c, qkv, nullptr, ROWS, EDIM, EDIM, EDIM, EDIM, QKV_N, 0, 0, 0,
       0, 0, 0, 1, 1, 2);
  gemm(enc_o, wqkv_c + EDIM * EDIM, qkv + EDIM, nullptr, ROWS, 2 * EDIM, EDIM,
       EDIM, EDIM, QKV_N, 0, 0, 0, 0, 0, 0, 1, 1, 2);
  attention(0);
  gemm(att, t_cdw, tmp, dec_cdb, ROWS, EDIM, EDIM, EDIM, EDIM, EDIM, 0, 0, 0,
       0, 0, 0, 1, 1, 2);
  add_ln_k<<<dim3(ROWS), dim3(256), 0, stream>>>(h1, tmp, dec_ln_g, dec_ln_b,
                                                 h2, 0);

  // ---- decoder FF + relu(LN) ----
  gemm(h2, t_decff, tmp, dec_ffb, ROWS, EDIM, EDIM, EDIM, EDIM, EDIM, 0, 0, 0,
       0, 0, 0, 1, 1, 2);
  add_ln_k<<<dim3(ROWS), dim3(256), 0, stream>>>(h2, tmp, dec_ln_g, dec_ln_b,
                                                 dec_o, 1);

  // ---- classifier (256^2 phase-split pipelined GEMM) ----
  gemm_big_l(dec_o, w1t, hid, cls_b1, ROWS, HID2, EDIM, EDIM, EDIM, HID2,
             HID2 - 1, 3);  // relu + bf16 out
  gemm_big_l(hid, w2t, d_out, cls_b2, ROWS, TGTV, HID2, HID2, HID2, TGTV,
             8063, 0);  // f32 out
}